// Round 5
// baseline (67.975 us; speedup 1.0000x reference)
//
#include <hip/hip_runtime.h>

// Problem constants (from reference)
#define B_    16
#define N_    25200
#define NC_   80
#define NM_   32
#define NDET_ 100
#define H_    160
#define W_    160
#define HW_   (H_ * W_)
#define XDIM_ (5 + NC_ + NM_)   // 117
#define COEF_OFF_ (5 + NC_)     // 85

// Output layout (flat f32):
#define OFF_BOXES_   16
#define OFF_SCORES_  6416
#define OFF_CLASSES_ 8016
#define OFF_MASKS_   9616

// Workspace layout (floats): [0, 51200) dense coefs [b][o][m]; [51200, 57600) scaled boxes [b][o][4]
#define WS_COEF_   0
#define WS_BOX_    (B_ * NDET_ * NM_)          // 51200
#define GATHER_N_  (B_ * NDET_ * NM_)          // 51200
#define BOXSC_N_   (B_ * NDET_ * 4)            // 6400
#define HEAD_N_    OFF_MASKS_                  // 9616
#define PREP_TOT_  (GATHER_N_ + BOXSC_N_ + HEAD_N_)

typedef float f32x4 __attribute__((ext_vector_type(4)));

__device__ inline float rl(float v, int lane) {
    return __uint_as_float(__builtin_amdgcn_readlane(__float_as_uint(v), lane));
}

// Pre-pass: gather dense coefs, prescale boxes into ws, write small head outputs.
__global__ __launch_bounds__(256) void prep_kernel(
    const float* __restrict__ x0,
    const int*   __restrict__ num_det,
    const float* __restrict__ det_boxes,
    const float* __restrict__ det_scores,
    const int*   __restrict__ det_classes,
    const int*   __restrict__ det_indices,
    float* __restrict__ ws,
    float* __restrict__ out)
{
    int i = blockIdx.x * 256 + threadIdx.x;
    if (i < GATHER_N_) {
        int b = i / (NDET_ * NM_);
        int rem = i - b * (NDET_ * NM_);
        int o = rem >> 5;
        int m = rem & 31;
        int idx = det_indices[b * NDET_ + o];
        ws[WS_COEF_ + i] = x0[((size_t)b * N_ + idx) * XDIM_ + COEF_OFF_ + m];
    } else if (i < GATHER_N_ + BOXSC_N_) {
        int j = i - GATHER_N_;
        ws[WS_BOX_ + j] = det_boxes[j] * 0.25f;
    } else if (i < PREP_TOT_) {
        int j = i - (GATHER_N_ + BOXSC_N_);
        if (j < 16) {
            out[j] = (float)num_det[j];
        } else if (j < OFF_SCORES_) {
            out[j] = det_boxes[j - OFF_BOXES_];
        } else if (j < OFF_CLASSES_) {
            out[j] = det_scores[j - OFF_SCORES_];
        } else {
            out[j] = (float)det_classes[j - OFF_CLASSES_];
        }
    }
}

// Main: 1 px/thread, 256-thread blocks, grid (100 tiles, 16 batches) = 6400 waves.
// Boxes lane-striped + v_readlane broadcast (no per-iteration memory load);
// coefs via wave-uniform scalar loads from dense ws; nt loads/stores for the
// zero-reuse streams (proto in, masks out) to keep L2 for ws.
__global__ __launch_bounds__(256) void mask_kernel(
    const float* __restrict__ proto,
    const float* __restrict__ ws,
    float* __restrict__ out)
{
    const int b    = blockIdx.y;
    const int tile = blockIdx.x;
    const int tid  = threadIdx.x;
    const int lane = tid & 63;

    const int p = tile * 256 + tid;
    const float rf = (float)(p % W_);
    const float cf = (float)(p / W_);

    // Lane-striped prescaled boxes: lane l holds det l (lo) and det 64+min(l,35) (hi).
    const f32x4* __restrict__ wsbox = (const f32x4*)(ws + WS_BOX_) + b * NDET_;
    const f32x4 blo = wsbox[lane];
    const f32x4 bhi = wsbox[64 + (lane < 36 ? lane : 35)];

    // This pixel's proto column (32 values) in registers; pure streaming -> nt.
    const float* __restrict__ pp = proto + (size_t)b * NM_ * HW_ + p;
    float pr[NM_];
#pragma unroll
    for (int m = 0; m < NM_; ++m)
        pr[m] = __builtin_nontemporal_load(pp + (size_t)m * HW_);

    const float* __restrict__ coef = ws + WS_COEF_ + b * NDET_ * NM_;
    float* __restrict__ outp = out + OFF_MASKS_ + (size_t)b * NDET_ * HW_ + p;

    for (int o = 0; o < 64; ++o) {
        const float x1 = rl(blo.x, o), y1 = rl(blo.y, o);
        const float x2 = rl(blo.z, o), y2 = rl(blo.w, o);
        const bool in = (rf >= x1) & (rf < x2) & (cf >= y1) & (cf < y2);
        float v = 0.0f;
        if (__ballot(in) != 0) {
            const float* __restrict__ cfp = coef + o * NM_;   // uniform -> s_load
            float acc = 0.0f;
#pragma unroll
            for (int m = 0; m < NM_; ++m) acc += cfp[m] * pr[m];
            const float s = 1.0f / (1.0f + __expf(-acc));
            v = in ? s : 0.0f;
        }
        __builtin_nontemporal_store(v, outp + (size_t)o * HW_);
    }
    for (int o = 64; o < NDET_; ++o) {
        const int l = o - 64;
        const float x1 = rl(bhi.x, l), y1 = rl(bhi.y, l);
        const float x2 = rl(bhi.z, l), y2 = rl(bhi.w, l);
        const bool in = (rf >= x1) & (rf < x2) & (cf >= y1) & (cf < y2);
        float v = 0.0f;
        if (__ballot(in) != 0) {
            const float* __restrict__ cfp = coef + o * NM_;
            float acc = 0.0f;
#pragma unroll
            for (int m = 0; m < NM_; ++m) acc += cfp[m] * pr[m];
            const float s = 1.0f / (1.0f + __expf(-acc));
            v = in ? s : 0.0f;
        }
        __builtin_nontemporal_store(v, outp + (size_t)o * HW_);
    }
}

extern "C" void kernel_launch(void* const* d_in, const int* in_sizes, int n_in,
                              void* d_out, int out_size, void* d_ws, size_t ws_size,
                              hipStream_t stream)
{
    const float* x0          = (const float*)d_in[0];
    const float* proto       = (const float*)d_in[1];
    const int*   num_det     = (const int*)  d_in[2];
    const float* det_boxes   = (const float*)d_in[3];
    const float* det_scores  = (const float*)d_in[4];
    const int*   det_classes = (const int*)  d_in[5];
    const int*   det_indices = (const int*)  d_in[6];
    float* out = (float*)d_out;
    float* ws  = (float*)d_ws;

    prep_kernel<<<(PREP_TOT_ + 255) / 256, 256, 0, stream>>>(
        x0, num_det, det_boxes, det_scores, det_classes, det_indices, ws, out);

    dim3 grid(HW_ / 256, B_);
    mask_kernel<<<grid, 256, 0, stream>>>(proto, ws, out);
}

// Round 6
// 45.481 us; speedup vs baseline: 1.4946x; 1.4946x over previous
//
#include <hip/hip_runtime.h>

// Problem constants (from reference)
#define B_    16
#define N_    25200
#define NC_   80
#define NM_   32
#define NDET_ 100
#define H_    160
#define W_    160
#define HW_   (H_ * W_)
#define XDIM_ (5 + NC_ + NM_)   // 117
#define COEF_OFF_ (5 + NC_)     // 85

// Output layout (flat f32):
#define OFF_BOXES_   16
#define OFF_SCORES_  6416
#define OFF_CLASSES_ 8016
#define OFF_MASKS_   9616

typedef float f32x4 __attribute__((ext_vector_type(4)));

// Single fused kernel. Grid (HW/256 = 100 tiles, B = 16) = 1600 blocks, 1 px/thread.
// All per-detection data (box, index, 32 coefs) is wave-uniform -> scalar-pipe
// loads (s_load) directly from the inputs; no prep pass, no LDS, plain VMEM
// loads/stores (nontemporal hints measurably regress on gfx950 - R2/R4/R5).
__global__ __launch_bounds__(256) void mask_kernel(
    const float* __restrict__ x0,
    const float* __restrict__ proto,
    const int*   __restrict__ num_det,
    const float* __restrict__ det_boxes,
    const float* __restrict__ det_scores,
    const int*   __restrict__ det_classes,
    const int*   __restrict__ det_indices,
    float* __restrict__ out)
{
    const int b    = blockIdx.y;
    const int tile = blockIdx.x;
    const int tid  = threadIdx.x;

    // Fused head outputs (tile-0 block of each batch writes the small outputs).
    if (tile == 0) {
        if (tid == 0) out[b] = (float)num_det[b];
        for (int i = tid; i < NDET_ * 4; i += 256)
            out[OFF_BOXES_ + b * NDET_ * 4 + i] = det_boxes[b * NDET_ * 4 + i];
        for (int i = tid; i < NDET_; i += 256) {
            out[OFF_SCORES_  + b * NDET_ + i] = det_scores[b * NDET_ + i];
            out[OFF_CLASSES_ + b * NDET_ + i] = (float)det_classes[b * NDET_ + i];
        }
    }

    const int p = tile * 256 + tid;
    const float rf = (float)(p % W_);
    const float cf = (float)(p / W_);

    // This pixel's proto column (32 values) in registers, coalesced plain loads.
    const float* __restrict__ pp = proto + (size_t)b * NM_ * HW_ + p;
    float pr[NM_];
#pragma unroll
    for (int m = 0; m < NM_; ++m) pr[m] = pp[(size_t)m * HW_];

    const f32x4* __restrict__ sbox = (const f32x4*)det_boxes + b * NDET_;
    const int*   __restrict__ dind = det_indices + b * NDET_;

    float* __restrict__ outp = out + OFF_MASKS_ + (size_t)b * NDET_ * HW_ + p;

    for (int o = 0; o < NDET_; ++o) {
        const f32x4 bx = sbox[o];                     // uniform -> s_load_dwordx4
        const float x1 = bx.x * 0.25f, y1 = bx.y * 0.25f;
        const float x2 = bx.z * 0.25f, y2 = bx.w * 0.25f;
        const bool in = (rf >= x1) & (rf < x2) & (cf >= y1) & (cf < y2);
        float v = 0.0f;
        if (__ballot(in) != 0) {
            // Force the row index onto the scalar pipe so the coef reads are s_loads.
            const int idx = __builtin_amdgcn_readfirstlane(dind[o]);
            const float* __restrict__ cfp =
                x0 + ((size_t)b * N_ + idx) * XDIM_ + COEF_OFF_;
            float acc = 0.0f;
#pragma unroll
            for (int m = 0; m < NM_; ++m) acc += cfp[m] * pr[m];
            const float s = 1.0f / (1.0f + __expf(-acc));
            v = in ? s : 0.0f;
        }
        outp[(size_t)o * HW_] = v;
    }
}

extern "C" void kernel_launch(void* const* d_in, const int* in_sizes, int n_in,
                              void* d_out, int out_size, void* d_ws, size_t ws_size,
                              hipStream_t stream)
{
    const float* x0          = (const float*)d_in[0];
    const float* proto       = (const float*)d_in[1];
    const int*   num_det     = (const int*)  d_in[2];
    const float* det_boxes   = (const float*)d_in[3];
    const float* det_scores  = (const float*)d_in[4];
    const int*   det_classes = (const int*)  d_in[5];
    const int*   det_indices = (const int*)  d_in[6];
    float* out = (float*)d_out;

    dim3 grid(HW_ / 256, B_);
    mask_kernel<<<grid, 256, 0, stream>>>(
        x0, proto, num_det, det_boxes, det_scores, det_classes, det_indices, out);
}

// Round 7
// 39.195 us; speedup vs baseline: 1.7343x; 1.1604x over previous
//
#include <hip/hip_runtime.h>

// Problem constants (from reference)
#define B_    16
#define N_    25200
#define NC_   80
#define NM_   32
#define NDET_ 100
#define H_    160
#define W_    160
#define HW_   (H_ * W_)
#define XDIM_ (5 + NC_ + NM_)   // 117
#define COEF_OFF_ (5 + NC_)     // 85

// Output layout (flat f32):
#define OFF_BOXES_   16
#define OFF_SCORES_  6416
#define OFF_CLASSES_ 8016
#define OFF_MASKS_   9616

#define ODET_ (NDET_ / 4)       // 25 detections per wave

typedef float f32x4 __attribute__((ext_vector_type(4)));

// Single fused kernel. Block = 4 waves; each wave owns 64 pixels x 25 detections.
// Grid (HW/64 = 400 tiles, B = 16) = 6400 blocks = 25600 waves (4x TLP vs R6).
// Per-detection data stays on the scalar pipe; plain loads/stores (nt regresses).
__global__ __launch_bounds__(256) void mask_kernel(
    const float* __restrict__ x0,
    const float* __restrict__ proto,
    const int*   __restrict__ num_det,
    const float* __restrict__ det_boxes,
    const float* __restrict__ det_scores,
    const int*   __restrict__ det_classes,
    const int*   __restrict__ det_indices,
    float* __restrict__ out)
{
    const int b    = blockIdx.y;
    const int tile = blockIdx.x;
    const int tid  = threadIdx.x;
    const int lane = tid & 63;
    const int wave = __builtin_amdgcn_readfirstlane(tid >> 6);

    // Fused head outputs (tile-0 block of each batch writes the small outputs).
    if (tile == 0) {
        if (tid == 0) out[b] = (float)num_det[b];
        for (int i = tid; i < NDET_ * 4; i += 256)
            out[OFF_BOXES_ + b * NDET_ * 4 + i] = det_boxes[b * NDET_ * 4 + i];
        for (int i = tid; i < NDET_; i += 256) {
            out[OFF_SCORES_  + b * NDET_ + i] = det_scores[b * NDET_ + i];
            out[OFF_CLASSES_ + b * NDET_ + i] = (float)det_classes[b * NDET_ + i];
        }
    }

    const int p = tile * 64 + lane;
    const float rf = (float)(p % W_);
    const float cf = (float)(p / W_);

    // This wave's 64 proto columns (32 values each) in registers; extra copies
    // across the block's 4 waves hit L1/L2, HBM fetch unchanged.
    const float* __restrict__ pp = proto + (size_t)b * NM_ * HW_ + p;
    float pr[NM_];
#pragma unroll
    for (int m = 0; m < NM_; ++m) pr[m] = pp[(size_t)m * HW_];

    const int o0 = wave * ODET_;
    const f32x4* __restrict__ sbox = (const f32x4*)det_boxes + b * NDET_ + o0;
    const int*   __restrict__ dind = det_indices + b * NDET_ + o0;

    float* __restrict__ outp =
        out + OFF_MASKS_ + ((size_t)b * NDET_ + o0) * HW_ + p;

    for (int i = 0; i < ODET_; ++i) {
        const f32x4 bx = sbox[i];                     // uniform -> s_load_dwordx4
        const float x1 = bx.x * 0.25f, y1 = bx.y * 0.25f;
        const float x2 = bx.z * 0.25f, y2 = bx.w * 0.25f;
        const bool in = (rf >= x1) & (rf < x2) & (cf >= y1) & (cf < y2);
        float v = 0.0f;
        if (__ballot(in) != 0) {
            const int idx = __builtin_amdgcn_readfirstlane(dind[i]);
            const float* __restrict__ cfp =
                x0 + ((size_t)b * N_ + idx) * XDIM_ + COEF_OFF_;
            float acc = 0.0f;
#pragma unroll
            for (int m = 0; m < NM_; ++m) acc += cfp[m] * pr[m];
            const float s = 1.0f / (1.0f + __expf(-acc));
            v = in ? s : 0.0f;
        }
        outp[(size_t)i * HW_] = v;
    }
}

extern "C" void kernel_launch(void* const* d_in, const int* in_sizes, int n_in,
                              void* d_out, int out_size, void* d_ws, size_t ws_size,
                              hipStream_t stream)
{
    const float* x0          = (const float*)d_in[0];
    const float* proto       = (const float*)d_in[1];
    const int*   num_det     = (const int*)  d_in[2];
    const float* det_boxes   = (const float*)d_in[3];
    const float* det_scores  = (const float*)d_in[4];
    const int*   det_classes = (const int*)  d_in[5];
    const int*   det_indices = (const int*)  d_in[6];
    float* out = (float*)d_out;

    dim3 grid(HW_ / 64, B_);
    mask_kernel<<<grid, 256, 0, stream>>>(
        x0, proto, num_det, det_boxes, det_scores, det_classes, det_indices, out);
}